// Round 1
// baseline (468.264 us; speedup 1.0000x reference)
//
#include <hip/hip_runtime.h>

// Problem constants (match reference)
#define B_    16
#define C_    80
#define H_    128
#define W_    128
#define N_    50
#define CAND_ 100
#define HW_   (H_*W_)
#define ONE_V_ 0.60653065971263342f   // exp(-0.5)
#define TWO_V_ 0.36787944117144233f   // exp(-1.0)
#define TK_P  16                      // partitions per batch in target kernel

// ws layout: acc[0]=focal sum, acc[1]=offset sum, acc[2]=size sum (doubles), then int count

__device__ __forceinline__ float block_reduce(float v, float* sbuf) {
    __syncthreads();                       // protect sbuf reuse across calls
    #pragma unroll
    for (int o = 32; o > 0; o >>= 1) v += __shfl_down(v, o, 64);
    int lane = threadIdx.x & 63;
    int wid  = threadIdx.x >> 6;
    if (lane == 0) sbuf[wid] = v;
    __syncthreads();
    float r = 0.0f;
    int nw = blockDim.x >> 6;
    if (wid == 0) {
        if (lane < nw) r = sbuf[lane];
        #pragma unroll
        for (int o = 32; o > 0; o >>= 1) r += __shfl_down(r, o, 64);
    }
    return r;  // valid on thread 0
}

__global__ void init_ws(double* acc, int* cnt) {
    int t = threadIdx.x;
    if (t < 3) acc[t] = 0.0;
    if (t == 3) *cnt = 0;
}

// gt==0 base focal term for every cell: p^2 * log(1-p)
__global__ __launch_bounds__(256) void focal_base_kernel(
        const float4* __restrict__ cp, double* __restrict__ acc) {
    __shared__ float sbuf[4];
    size_t idx = (size_t)blockIdx.x * 256 + threadIdx.x;
    float4 v = cp[idx];
    float s = 0.0f;
    {
        float p = fminf(fmaxf(v.x, 1e-4f), 0.9999f); s += p*p*__logf(1.0f - p);
        p = fminf(fmaxf(v.y, 1e-4f), 0.9999f);       s += p*p*__logf(1.0f - p);
        p = fminf(fmaxf(v.z, 1e-4f), 0.9999f);       s += p*p*__logf(1.0f - p);
        p = fminf(fmaxf(v.w, 1e-4f), 0.9999f);       s += p*p*__logf(1.0f - p);
    }
    float r = block_reduce(s, sbuf);
    if (threadIdx.x == 0) atomicAdd(&acc[0], (double)r);
}

// Sparse heatmap correction: for each unique gt>0 cell, replace base term with the true term.
__global__ __launch_bounds__(256) void heat_kernel(
        const float* __restrict__ cls_pred,
        const float* __restrict__ gt_box,
        const int* __restrict__ gt_class,
        double* __restrict__ acc) {
    __shared__ int   ekey[9*N_];
    __shared__ float evalv[9*N_];
    __shared__ float sbuf[4];
    int b = blockIdx.x;
    int tid = threadIdx.x;
    for (int e = tid; e < 9*N_; e += 256) ekey[e] = -1;
    __syncthreads();
    if (tid < N_) {
        int n = tid;
        int gc = gt_class[b*N_ + n];
        if (gc != -1) {
            int ch = gc < 0 ? 0 : gc;
            const float* bx = gt_box + ((size_t)b*N_ + n)*4;
            float wv = bx[2] - bx[0];
            float hv = bx[3] - bx[1];
            int cx = (int)floorf(floorf(wv*0.5f)*0.25f);
            int cy = (int)floorf(floorf(hv*0.5f)*0.25f);
            if (cx >= 0 && cx < H_ && cy >= 0 && cy < W_) {
                ekey[n*9]  = (ch*H_ + cx)*W_ + cy;
                evalv[n*9] = 1.0f;
            }
            bool interior = (cx >= 1) && (cy >= 1) && (cx + 1 < H_) && (cy + 1 < W_);
            if (interior) {
                const int   dxs[8] = {-1,-1,-1, 0, 0, 1, 1, 1};
                const int   dys[8] = {-1, 0, 1,-1, 1,-1, 0, 1};
                const float vvs[8] = {TWO_V_,ONE_V_,TWO_V_,ONE_V_,ONE_V_,TWO_V_,ONE_V_,TWO_V_};
                #pragma unroll
                for (int q = 0; q < 8; q++) {
                    ekey[n*9+1+q]  = (ch*H_ + cx + dxs[q])*W_ + (cy + dys[q]);
                    evalv[n*9+1+q] = vvs[q];
                }
            }
        }
    }
    __syncthreads();
    float corr = 0.0f;
    for (int e = tid; e < 9*N_; e += 256) {
        int k = ekey[e];
        if (k < 0) continue;
        bool owner = true;
        for (int q = 0; q < e; q++) if (ekey[q] == k) { owner = false; break; }
        if (!owner) continue;
        float g = evalv[e];
        for (int q = e + 1; q < 9*N_; q++) if (ekey[q] == k) g = fmaxf(g, evalv[q]);
        float praw = cls_pred[(size_t)b*C_*HW_ + k];
        float p  = fminf(fmaxf(praw, 1e-4f), 0.9999f);
        float lm = __logf(1.0f - p);
        float base = p*p*lm;
        float actual;
        if (g == 1.0f) {
            float q1 = 1.0f - p; float q2 = q1*q1;
            actual = q2*q2*__logf(p);
        } else {
            float q1 = 1.0f - g; float q2 = q1*q1;
            actual = q2*q2*p*p*lm;
        }
        corr += actual - base;
    }
    float rc = block_reduce(corr, sbuf);
    if (tid == 0) atomicAdd(&acc[0], (double)rc);
}

// _target_one: exact-rank selection of CAND smallest cls_pred in the window,
// directly accumulating offset/size L1 sums and num_pos.
__global__ __launch_bounds__(256) void target_kernel(
        const float* __restrict__ cls_pred,
        const float* __restrict__ offset_pred,
        const float* __restrict__ size_pred,
        const float* __restrict__ gt_box,
        const int* __restrict__ gt_class,
        double* __restrict__ acc, int* __restrict__ cnt) {
    __shared__ float svals[4096];   // window <= 64x64 (right<=H/2, bottom<=W/2)
    __shared__ float sbuf[4];
    int b    = blockIdx.x / TK_P;
    int part = blockIdx.x % TK_P;
    int tid  = threadIdx.x;

    // per-batch scalars (computed redundantly by all threads; L1-cached reads)
    int last = -1; bool anyv = false;
    for (int n = 0; n < N_; n++) {
        if (gt_class[b*N_ + n] != -1) { anyv = true; last = n; }
    }
    int lastc = last < 0 ? 0 : last;
    const float* bx = gt_box + ((size_t)b*N_ + lastc)*4;
    float wv = bx[2] - bx[0];
    float hv = bx[3] - bx[1];
    int gc = gt_class[b*N_ + lastc];
    int ch = gc < 0 ? 0 : gc;
    int cx = (int)floorf(floorf(wv*0.5f)*0.25f);
    int cy = (int)floorf(floorf(hv*0.5f)*0.25f);
    int w4 = (int)floorf(wv*0.25f);
    int h4 = (int)floorf(hv*0.25f);
    // Python // is floor division: >>1 (arithmetic shift) matches for all signs
    int left   = max((cx - (w4 >> 1)) >> 1, 0);
    int right  = min((cx + (w4 >> 1)) >> 1, H_/2);
    int top    = max((cy - (h4 >> 1)) >> 1, 0);
    int bottom = min((cy + (h4 >> 1)) >> 1, W_/2);
    int Mw = right - left, Mh = bottom - top;
    int M = (anyv && Mw > 0 && Mh > 0) ? Mw * Mh : 0;

    float offsum = 0.0f, sizsum = 0.0f; float csum = 0.0f;
    if (M > 0) {
        const float* cp = cls_pred + ((size_t)b*C_ + ch)*HW_;
        for (int t = tid; t < M; t += 256) {
            int i = left + t / Mh;
            int j = top  + t % Mh;
            svals[t] = cp[i*W_ + j];
        }
        __syncthreads();
        float cxf = wv * 0.125f, cyf = hv * 0.125f;   // wv/2/4 exact in fp32
        float off0 = cxf - floorf(cxf);
        float off1 = cyf - floorf(cyf);
        for (int t = part*256 + tid; t < M; t += TK_P*256) {
            float v = svals[t];
            int rank = 0;
            for (int k = 0; k < M; k++) {
                float u = svals[k];                    // wave-uniform k -> LDS broadcast
                rank += (u < v) || (u == v && k < t);  // tie-break = lower flat idx, as top_k
            }
            if (rank < CAND_) {
                int i = left + t / Mh;
                int j = top  + t % Mh;
                const float* op = offset_pred + (size_t)b*2*HW_ + i*W_ + j;
                const float* sp = size_pred   + (size_t)b*2*HW_ + i*W_ + j;
                offsum += fabsf(op[0]   - off0) + fabsf(op[HW_] - off1);
                sizsum += fabsf(sp[0]   - wv)   + fabsf(sp[HW_] - hv);
                csum   += 1.0f;
            }
        }
    }
    float ro = block_reduce(offsum, sbuf);
    float rs = block_reduce(sizsum, sbuf);
    float rc = block_reduce(csum,   sbuf);
    if (tid == 0) {
        if (ro != 0.0f) atomicAdd(&acc[1], (double)ro);
        if (rs != 0.0f) atomicAdd(&acc[2], (double)rs);
        if (rc != 0.0f) atomicAdd(cnt, (int)(rc + 0.5f));
    }
}

__global__ void finalize_kernel(const double* __restrict__ acc,
                                const int* __restrict__ cnt,
                                float* __restrict__ out) {
    if (blockIdx.x == 0 && threadIdx.x == 0) {
        int c = *cnt;
        double np_ = (double)(c < 1 ? 1 : c);
        double cls = -acc[0] / (double)(B_*H_*W_);
        out[0] = (float)(cls + acc[1]/np_ + 0.1*acc[2]/np_);
    }
}

extern "C" void kernel_launch(void* const* d_in, const int* in_sizes, int n_in,
                              void* d_out, int out_size, void* d_ws, size_t ws_size,
                              hipStream_t stream) {
    const float* cls_pred    = (const float*)d_in[0];
    const float* offset_pred = (const float*)d_in[1];
    const float* size_pred   = (const float*)d_in[2];
    const float* gt_box      = (const float*)d_in[3];
    const int*   gt_class    = (const int*)d_in[4];
    float* out  = (float*)d_out;
    double* acc = (double*)d_ws;
    int*    cnt = (int*)((char*)d_ws + 3*sizeof(double));

    init_ws<<<dim3(1), dim3(64), 0, stream>>>(acc, cnt);
    focal_base_kernel<<<dim3((B_*C_*HW_)/4/256), dim3(256), 0, stream>>>(
        (const float4*)cls_pred, acc);
    target_kernel<<<dim3(B_*TK_P), dim3(256), 0, stream>>>(
        cls_pred, offset_pred, size_pred, gt_box, gt_class, acc, cnt);
    heat_kernel<<<dim3(B_), dim3(256), 0, stream>>>(
        cls_pred, gt_box, gt_class, acc);
    finalize_kernel<<<dim3(1), dim3(1), 0, stream>>>(acc, cnt, out);
}

// Round 2
// 246.396 us; speedup vs baseline: 1.9005x; 1.9005x over previous
//
#include <hip/hip_runtime.h>

// Problem constants (match reference)
#define B_    16
#define C_    80
#define H_    128
#define W_    128
#define N_    50
#define CAND_ 100
#define HW_   (H_*W_)
#define ONE_V_ 0.60653065971263342f   // exp(-0.5)
#define TWO_V_ 0.36787944117144233f   // exp(-1.0)
#define TK_P  16                      // partitions per batch in target kernel

#define FOCAL_ITERS   16
#define FOCAL_BLOCKS  ((B_*C_*HW_) / 4 / 256 / FOCAL_ITERS)   // 1280

// ws layout: double acc[3] (heat-corr, offset-sum, size-sum), int cnt, pad,
//            float partial[FOCAL_BLOCKS] at byte offset 32.

__device__ __forceinline__ float block_reduce(float v, float* sbuf) {
    __syncthreads();
    #pragma unroll
    for (int o = 32; o > 0; o >>= 1) v += __shfl_down(v, o, 64);
    int lane = threadIdx.x & 63;
    int wid  = threadIdx.x >> 6;
    if (lane == 0) sbuf[wid] = v;
    __syncthreads();
    float r = 0.0f;
    int nw = blockDim.x >> 6;
    if (wid == 0) {
        if (lane < nw) r = sbuf[lane];
        #pragma unroll
        for (int o = 32; o > 0; o >>= 1) r += __shfl_down(r, o, 64);
    }
    return r;  // valid on thread 0
}

__global__ void init_ws(double* acc, int* cnt) {
    int t = threadIdx.x;
    if (t < 3) acc[t] = 0.0;
    if (t == 3) *cnt = 0;
}

// gt==0 base focal term for every cell: p^2 * log(1-p).
// Two-stage reduction: per-block partial -> ws (NO same-address atomics;
// 20480 serialized f64 atomics cost 251us in R1).
__global__ __launch_bounds__(256) void focal_base_kernel(
        const float4* __restrict__ cp, float* __restrict__ partial) {
    __shared__ float sbuf[4];
    size_t base = (size_t)blockIdx.x * 256 * FOCAL_ITERS + threadIdx.x;
    float s = 0.0f;
    #pragma unroll
    for (int it = 0; it < FOCAL_ITERS; it++) {
        float4 v = cp[base + (size_t)it * 256];
        float p;
        p = fminf(fmaxf(v.x, 1e-4f), 0.9999f); s += p*p*__logf(1.0f - p);
        p = fminf(fmaxf(v.y, 1e-4f), 0.9999f); s += p*p*__logf(1.0f - p);
        p = fminf(fmaxf(v.z, 1e-4f), 0.9999f); s += p*p*__logf(1.0f - p);
        p = fminf(fmaxf(v.w, 1e-4f), 0.9999f); s += p*p*__logf(1.0f - p);
    }
    float r = block_reduce(s, sbuf);
    if (threadIdx.x == 0) partial[blockIdx.x] = r;
}

// Sparse heatmap correction: for each unique gt>0 cell, replace base term with the true term.
__global__ __launch_bounds__(256) void heat_kernel(
        const float* __restrict__ cls_pred,
        const float* __restrict__ gt_box,
        const int* __restrict__ gt_class,
        double* __restrict__ acc) {
    __shared__ int   ekey[9*N_];
    __shared__ float evalv[9*N_];
    __shared__ float sbuf[4];
    int b = blockIdx.x;
    int tid = threadIdx.x;
    for (int e = tid; e < 9*N_; e += 256) ekey[e] = -1;
    __syncthreads();
    if (tid < N_) {
        int n = tid;
        int gc = gt_class[b*N_ + n];
        if (gc != -1) {
            int ch = gc < 0 ? 0 : gc;
            const float* bx = gt_box + ((size_t)b*N_ + n)*4;
            float wv = bx[2] - bx[0];
            float hv = bx[3] - bx[1];
            int cx = (int)floorf(floorf(wv*0.5f)*0.25f);
            int cy = (int)floorf(floorf(hv*0.5f)*0.25f);
            if (cx >= 0 && cx < H_ && cy >= 0 && cy < W_) {
                ekey[n*9]  = (ch*H_ + cx)*W_ + cy;
                evalv[n*9] = 1.0f;
            }
            bool interior = (cx >= 1) && (cy >= 1) && (cx + 1 < H_) && (cy + 1 < W_);
            if (interior) {
                const int   dxs[8] = {-1,-1,-1, 0, 0, 1, 1, 1};
                const int   dys[8] = {-1, 0, 1,-1, 1,-1, 0, 1};
                const float vvs[8] = {TWO_V_,ONE_V_,TWO_V_,ONE_V_,ONE_V_,TWO_V_,ONE_V_,TWO_V_};
                #pragma unroll
                for (int q = 0; q < 8; q++) {
                    ekey[n*9+1+q]  = (ch*H_ + cx + dxs[q])*W_ + (cy + dys[q]);
                    evalv[n*9+1+q] = vvs[q];
                }
            }
        }
    }
    __syncthreads();
    float corr = 0.0f;
    for (int e = tid; e < 9*N_; e += 256) {
        int k = ekey[e];
        if (k < 0) continue;
        bool owner = true;
        for (int q = 0; q < e; q++) if (ekey[q] == k) { owner = false; break; }
        if (!owner) continue;
        float g = evalv[e];
        for (int q = e + 1; q < 9*N_; q++) if (ekey[q] == k) g = fmaxf(g, evalv[q]);
        float praw = cls_pred[(size_t)b*C_*HW_ + k];
        float p  = fminf(fmaxf(praw, 1e-4f), 0.9999f);
        float lm = __logf(1.0f - p);
        float base = p*p*lm;
        float actual;
        if (g == 1.0f) {
            float q1 = 1.0f - p; float q2 = q1*q1;
            actual = q2*q2*__logf(p);
        } else {
            float q1 = 1.0f - g; float q2 = q1*q1;
            actual = q2*q2*p*p*lm;
        }
        corr += actual - base;
    }
    float rc = block_reduce(corr, sbuf);
    if (tid == 0 && rc != 0.0f) atomicAdd(&acc[0], (double)rc);
}

// _target_one: exact-rank selection of CAND smallest cls_pred in the window,
// directly accumulating offset/size L1 sums and num_pos.
__global__ __launch_bounds__(256) void target_kernel(
        const float* __restrict__ cls_pred,
        const float* __restrict__ offset_pred,
        const float* __restrict__ size_pred,
        const float* __restrict__ gt_box,
        const int* __restrict__ gt_class,
        double* __restrict__ acc, int* __restrict__ cnt) {
    __shared__ float svals[4096];   // window <= 64x64 (right<=H/2, bottom<=W/2)
    __shared__ float sbuf[4];
    int b    = blockIdx.x / TK_P;
    int part = blockIdx.x % TK_P;
    int tid  = threadIdx.x;

    int last = -1; bool anyv = false;
    for (int n = 0; n < N_; n++) {
        if (gt_class[b*N_ + n] != -1) { anyv = true; last = n; }
    }
    int lastc = last < 0 ? 0 : last;
    const float* bx = gt_box + ((size_t)b*N_ + lastc)*4;
    float wv = bx[2] - bx[0];
    float hv = bx[3] - bx[1];
    int gc = gt_class[b*N_ + lastc];
    int ch = gc < 0 ? 0 : gc;
    int cx = (int)floorf(floorf(wv*0.5f)*0.25f);
    int cy = (int)floorf(floorf(hv*0.5f)*0.25f);
    int w4 = (int)floorf(wv*0.25f);
    int h4 = (int)floorf(hv*0.25f);
    // Python // is floor division: >>1 (arithmetic shift) matches for all signs
    int left   = max((cx - (w4 >> 1)) >> 1, 0);
    int right  = min((cx + (w4 >> 1)) >> 1, H_/2);
    int top    = max((cy - (h4 >> 1)) >> 1, 0);
    int bottom = min((cy + (h4 >> 1)) >> 1, W_/2);
    int Mw = right - left, Mh = bottom - top;
    int M = (anyv && Mw > 0 && Mh > 0) ? Mw * Mh : 0;

    float offsum = 0.0f, sizsum = 0.0f; float csum = 0.0f;
    if (M > 0) {
        const float* cp = cls_pred + ((size_t)b*C_ + ch)*HW_;
        for (int t = tid; t < M; t += 256) {
            int i = left + t / Mh;
            int j = top  + t % Mh;
            svals[t] = cp[i*W_ + j];
        }
        __syncthreads();
        float cxf = wv * 0.125f, cyf = hv * 0.125f;   // wv/2/4 exact in fp32
        float off0 = cxf - floorf(cxf);
        float off1 = cyf - floorf(cyf);
        for (int t = part*256 + tid; t < M; t += TK_P*256) {
            float v = svals[t];
            int rank = 0;
            for (int k = 0; k < M; k++) {
                float u = svals[k];                    // wave-uniform k -> LDS broadcast
                rank += (u < v) || (u == v && k < t);  // tie-break = lower flat idx, as top_k
            }
            if (rank < CAND_) {
                int i = left + t / Mh;
                int j = top  + t % Mh;
                const float* op = offset_pred + (size_t)b*2*HW_ + i*W_ + j;
                const float* sp = size_pred   + (size_t)b*2*HW_ + i*W_ + j;
                offsum += fabsf(op[0]   - off0) + fabsf(op[HW_] - off1);
                sizsum += fabsf(sp[0]   - wv)   + fabsf(sp[HW_] - hv);
                csum   += 1.0f;
            }
        }
    }
    float ro = block_reduce(offsum, sbuf);
    float rs = block_reduce(sizsum, sbuf);
    float rc = block_reduce(csum,   sbuf);
    if (tid == 0) {
        if (ro != 0.0f) atomicAdd(&acc[1], (double)ro);
        if (rs != 0.0f) atomicAdd(&acc[2], (double)rs);
        if (rc != 0.0f) atomicAdd(cnt, (int)(rc + 0.5f));
    }
}

__global__ __launch_bounds__(256) void finalize_kernel(
        const float* __restrict__ partial,
        const double* __restrict__ acc,
        const int* __restrict__ cnt,
        float* __restrict__ out) {
    __shared__ double dbuf[4];
    int tid = threadIdx.x;
    double s = 0.0;
    for (int i = tid; i < FOCAL_BLOCKS; i += 256) s += (double)partial[i];
    #pragma unroll
    for (int o = 32; o > 0; o >>= 1) s += __shfl_down(s, o, 64);
    int lane = tid & 63, wid = tid >> 6;
    if (lane == 0) dbuf[wid] = s;
    __syncthreads();
    if (tid == 0) {
        double tot = dbuf[0] + dbuf[1] + dbuf[2] + dbuf[3];
        tot += acc[0];                        // sparse heatmap correction
        int c = *cnt;
        double np_ = (double)(c < 1 ? 1 : c);
        double cls = -tot / (double)(B_*H_*W_);
        out[0] = (float)(cls + acc[1]/np_ + 0.1*acc[2]/np_);
    }
}

extern "C" void kernel_launch(void* const* d_in, const int* in_sizes, int n_in,
                              void* d_out, int out_size, void* d_ws, size_t ws_size,
                              hipStream_t stream) {
    const float* cls_pred    = (const float*)d_in[0];
    const float* offset_pred = (const float*)d_in[1];
    const float* size_pred   = (const float*)d_in[2];
    const float* gt_box      = (const float*)d_in[3];
    const int*   gt_class    = (const int*)d_in[4];
    float* out  = (float*)d_out;
    double* acc = (double*)d_ws;
    int*    cnt = (int*)((char*)d_ws + 3*sizeof(double));
    float*  partial = (float*)((char*)d_ws + 32);

    init_ws<<<dim3(1), dim3(64), 0, stream>>>(acc, cnt);
    focal_base_kernel<<<dim3(FOCAL_BLOCKS), dim3(256), 0, stream>>>(
        (const float4*)cls_pred, partial);
    target_kernel<<<dim3(B_*TK_P), dim3(256), 0, stream>>>(
        cls_pred, offset_pred, size_pred, gt_box, gt_class, acc, cnt);
    heat_kernel<<<dim3(B_), dim3(256), 0, stream>>>(
        cls_pred, gt_box, gt_class, acc);
    finalize_kernel<<<dim3(1), dim3(256), 0, stream>>>(partial, acc, cnt, out);
}

// Round 3
// 168.629 us; speedup vs baseline: 2.7769x; 1.4612x over previous
//
#include <hip/hip_runtime.h>

// Problem constants (match reference)
#define B_    16
#define C_    80
#define H_    128
#define W_    128
#define N_    50
#define CAND_ 100
#define HW_   (H_*W_)
#define ONE_V_ 0.60653065971263342f   // exp(-0.5)
#define TWO_V_ 0.36787944117144233f   // exp(-1.0)
#define TK_P  16                      // partitions per batch in target part

#define FOCAL_ITERS   16
#define FOCAL_BLOCKS  ((B_*C_*HW_) / 4 / 256 / FOCAL_ITERS)   // 1280
#define TK_BLOCKS     (B_*TK_P)                               // 256
#define HEAT_BLOCKS   B_                                      // 16
#define TOTAL_BLOCKS  (FOCAL_BLOCKS + TK_BLOCKS + HEAT_BLOCKS)

// ws float layout (all partials written unconditionally every call):
//   [0,1280)     focal per-block partials
//   [1280,1536)  target offset-sum per-block
//   [1536,1792)  target size-sum per-block
//   [1792,2048)  target count per-block (as float)
//   [2048,2064)  heat correction per-batch
#define WS_TOFF 1280
#define WS_TSIZ 1536
#define WS_TCNT 1792
#define WS_HEAT 2048

__device__ __forceinline__ float block_reduce(float v, float* sbuf) {
    __syncthreads();                       // protect sbuf reuse across calls
    #pragma unroll
    for (int o = 32; o > 0; o >>= 1) v += __shfl_down(v, o, 64);
    int lane = threadIdx.x & 63;
    int wid  = threadIdx.x >> 6;
    if (lane == 0) sbuf[wid] = v;
    __syncthreads();
    float r = 0.0f;
    if (wid == 0) {
        if (lane < 4) r = sbuf[lane];
        #pragma unroll
        for (int o = 2; o > 0; o >>= 1) r += __shfl_down(r, o, 64);
    }
    return r;  // valid on thread 0
}

// One fused kernel: focal blocks + target blocks + heat blocks, all
// independent, all writing private ws slots (no atomics, no init kernel,
// concurrent execution instead of stream serialization).
__global__ __launch_bounds__(256) void main_kernel(
        const float* __restrict__ cls_pred,
        const float* __restrict__ offset_pred,
        const float* __restrict__ size_pred,
        const float* __restrict__ gt_box,
        const int* __restrict__ gt_class,
        float* __restrict__ ws) {
    __shared__ float smem[4096 + 1088];   // target svals | heat arrays | sbuf
    int bid = blockIdx.x;
    int tid = threadIdx.x;

    if (bid < FOCAL_BLOCKS) {
        // ---- focal base: gt==0 term p^2*log(1-p) for every cell ----
        float* sbuf = smem;
        const float4* cp = (const float4*)cls_pred;
        size_t base = (size_t)bid * 256 * FOCAL_ITERS + tid;
        float s = 0.0f;
        #pragma unroll
        for (int it = 0; it < FOCAL_ITERS; it++) {
            float4 v = cp[base + (size_t)it * 256];
            float p;
            p = fminf(fmaxf(v.x, 1e-4f), 0.9999f); s += p*p*__logf(1.0f - p);
            p = fminf(fmaxf(v.y, 1e-4f), 0.9999f); s += p*p*__logf(1.0f - p);
            p = fminf(fmaxf(v.z, 1e-4f), 0.9999f); s += p*p*__logf(1.0f - p);
            p = fminf(fmaxf(v.w, 1e-4f), 0.9999f); s += p*p*__logf(1.0f - p);
        }
        float r = block_reduce(s, sbuf);
        if (tid == 0) ws[bid] = r;

    } else if (bid < FOCAL_BLOCKS + TK_BLOCKS) {
        // ---- target: CAND smallest cls_pred in window -> L1 sums + count ----
        int tb   = bid - FOCAL_BLOCKS;
        int b    = tb / TK_P;
        int part = tb % TK_P;
        float* svals = smem;          // window <= 64x64
        float* sbuf  = smem + 4096;

        int last = -1; bool anyv = false;
        for (int n = 0; n < N_; n++) {
            if (gt_class[b*N_ + n] != -1) { anyv = true; last = n; }
        }
        int lastc = last < 0 ? 0 : last;
        const float* bx = gt_box + ((size_t)b*N_ + lastc)*4;
        float wv = bx[2] - bx[0];
        float hv = bx[3] - bx[1];
        int gc = gt_class[b*N_ + lastc];
        int ch = gc < 0 ? 0 : gc;
        int cx = (int)floorf(floorf(wv*0.5f)*0.25f);
        int cy = (int)floorf(floorf(hv*0.5f)*0.25f);
        int w4 = (int)floorf(wv*0.25f);
        int h4 = (int)floorf(hv*0.25f);
        // Python // is floor division: arithmetic >>1 matches for all signs
        int left   = max((cx - (w4 >> 1)) >> 1, 0);
        int right  = min((cx + (w4 >> 1)) >> 1, H_/2);
        int top    = max((cy - (h4 >> 1)) >> 1, 0);
        int bottom = min((cy + (h4 >> 1)) >> 1, W_/2);
        int Mw = right - left, Mh = bottom - top;
        int M = (anyv && Mw > 0 && Mh > 0) ? Mw * Mh : 0;

        float offsum = 0.0f, sizsum = 0.0f, csum = 0.0f;
        if (M > 0) {
            const float* cp = cls_pred + ((size_t)b*C_ + ch)*HW_;
            for (int t = tid; t < M; t += 256) {
                int i = left + t / Mh;
                int j = top  + t % Mh;
                svals[t] = cp[i*W_ + j];
            }
            __syncthreads();
            float cxf = wv * 0.125f, cyf = hv * 0.125f;   // wv/2/4 exact in fp32
            float off0 = cxf - floorf(cxf);
            float off1 = cyf - floorf(cyf);
            for (int t = part*256 + tid; t < M; t += TK_P*256) {
                float v = svals[t];
                int rank = 0;
                for (int k = 0; k < M; k++) {
                    float u = svals[k];                    // wave-uniform k -> LDS broadcast
                    rank += (u < v) || (u == v && k < t);  // tie-break = lower idx, as top_k
                }
                if (rank < CAND_) {
                    int i = left + t / Mh;
                    int j = top  + t % Mh;
                    const float* op = offset_pred + (size_t)b*2*HW_ + i*W_ + j;
                    const float* sp = size_pred   + (size_t)b*2*HW_ + i*W_ + j;
                    offsum += fabsf(op[0] - off0) + fabsf(op[HW_] - off1);
                    sizsum += fabsf(sp[0] - wv)   + fabsf(sp[HW_] - hv);
                    csum   += 1.0f;
                }
            }
        }
        float ro = block_reduce(offsum, sbuf);
        float rs = block_reduce(sizsum, sbuf);
        float rc = block_reduce(csum,   sbuf);
        if (tid == 0) {
            ws[WS_TOFF + tb] = ro;
            ws[WS_TSIZ + tb] = rs;
            ws[WS_TCNT + tb] = rc;
        }

    } else {
        // ---- heat: sparse correction of focal terms at gt>0 cells ----
        int b = bid - FOCAL_BLOCKS - TK_BLOCKS;
        int*   ekey  = (int*)smem;          // 9*N entries (<=450), pad to 512
        float* evalv = smem + 512;
        float* sbuf  = smem + 1024;
        for (int e = tid; e < 9*N_; e += 256) ekey[e] = -1;
        __syncthreads();
        if (tid < N_) {
            int n = tid;
            int gc = gt_class[b*N_ + n];
            if (gc != -1) {
                int ch = gc < 0 ? 0 : gc;
                const float* bx = gt_box + ((size_t)b*N_ + n)*4;
                float wv = bx[2] - bx[0];
                float hv = bx[3] - bx[1];
                int cx = (int)floorf(floorf(wv*0.5f)*0.25f);
                int cy = (int)floorf(floorf(hv*0.5f)*0.25f);
                if (cx >= 0 && cx < H_ && cy >= 0 && cy < W_) {
                    ekey[n*9]  = (ch*H_ + cx)*W_ + cy;
                    evalv[n*9] = 1.0f;
                }
                bool interior = (cx >= 1) && (cy >= 1) && (cx + 1 < H_) && (cy + 1 < W_);
                if (interior) {
                    const int   dxs[8] = {-1,-1,-1, 0, 0, 1, 1, 1};
                    const int   dys[8] = {-1, 0, 1,-1, 1,-1, 0, 1};
                    const float vvs[8] = {TWO_V_,ONE_V_,TWO_V_,ONE_V_,ONE_V_,TWO_V_,ONE_V_,TWO_V_};
                    #pragma unroll
                    for (int q = 0; q < 8; q++) {
                        ekey[n*9+1+q]  = (ch*H_ + cx + dxs[q])*W_ + (cy + dys[q]);
                        evalv[n*9+1+q] = vvs[q];
                    }
                }
            }
        }
        __syncthreads();
        float corr = 0.0f;
        for (int e = tid; e < 9*N_; e += 256) {
            int k = ekey[e];
            if (k < 0) continue;
            // Branch-free uniform scan (R2's early-break LDS loops serialized
            // at LDS latency -> 83us). g = per-key max; owner = first argmax.
            float g = 0.0f; int first = -1;
            for (int q = 0; q < 9*N_; q++) {
                bool hit = (ekey[q] == k) && (evalv[q] > g);
                g     = hit ? evalv[q] : g;
                first = hit ? q        : first;
            }
            if (first != e) continue;
            float praw = cls_pred[(size_t)b*C_*HW_ + k];
            float p  = fminf(fmaxf(praw, 1e-4f), 0.9999f);
            float lm = __logf(1.0f - p);
            float base = p*p*lm;
            float actual;
            if (g == 1.0f) {
                float q1 = 1.0f - p; float q2 = q1*q1;
                actual = q2*q2*__logf(p);
            } else {
                float q1 = 1.0f - g; float q2 = q1*q1;
                actual = q2*q2*p*p*lm;
            }
            corr += actual - base;
        }
        float rc = block_reduce(corr, sbuf);
        if (tid == 0) ws[WS_HEAT + b] = rc;
    }
}

__global__ __launch_bounds__(256) void finalize_kernel(
        const float* __restrict__ ws, float* __restrict__ out) {
    __shared__ double dbuf[16];
    int tid = threadIdx.x;
    double cls = 0.0, off = 0.0, siz = 0.0, cnt = 0.0;
    for (int i = tid; i < FOCAL_BLOCKS; i += 256) cls += (double)ws[i];
    if (tid < HEAT_BLOCKS) cls += (double)ws[WS_HEAT + tid];
    off = (double)ws[WS_TOFF + tid];
    siz = (double)ws[WS_TSIZ + tid];
    cnt = (double)ws[WS_TCNT + tid];
    int lane = tid & 63, wid = tid >> 6;
    #pragma unroll
    for (int o = 32; o > 0; o >>= 1) {
        cls += __shfl_down(cls, o, 64);
        off += __shfl_down(off, o, 64);
        siz += __shfl_down(siz, o, 64);
        cnt += __shfl_down(cnt, o, 64);
    }
    if (lane == 0) {
        dbuf[wid*4+0] = cls; dbuf[wid*4+1] = off;
        dbuf[wid*4+2] = siz; dbuf[wid*4+3] = cnt;
    }
    __syncthreads();
    if (tid == 0) {
        cls = dbuf[0] + dbuf[4] + dbuf[8]  + dbuf[12];
        off = dbuf[1] + dbuf[5] + dbuf[9]  + dbuf[13];
        siz = dbuf[2] + dbuf[6] + dbuf[10] + dbuf[14];
        cnt = dbuf[3] + dbuf[7] + dbuf[11] + dbuf[15];
        int c = (int)(cnt + 0.5);
        double np_ = (double)(c < 1 ? 1 : c);
        out[0] = (float)(-cls / (double)(B_*H_*W_) + off/np_ + 0.1*siz/np_);
    }
}

extern "C" void kernel_launch(void* const* d_in, const int* in_sizes, int n_in,
                              void* d_out, int out_size, void* d_ws, size_t ws_size,
                              hipStream_t stream) {
    const float* cls_pred    = (const float*)d_in[0];
    const float* offset_pred = (const float*)d_in[1];
    const float* size_pred   = (const float*)d_in[2];
    const float* gt_box      = (const float*)d_in[3];
    const int*   gt_class    = (const int*)d_in[4];
    float* out = (float*)d_out;
    float* ws  = (float*)d_ws;

    main_kernel<<<dim3(TOTAL_BLOCKS), dim3(256), 0, stream>>>(
        cls_pred, offset_pred, size_pred, gt_box, gt_class, ws);
    finalize_kernel<<<dim3(1), dim3(256), 0, stream>>>(ws, out);
}

// Round 4
// 153.729 us; speedup vs baseline: 3.0460x; 1.0969x over previous
//
#include <hip/hip_runtime.h>

// Problem constants (match reference)
#define B_    16
#define C_    80
#define H_    128
#define W_    128
#define N_    50
#define CAND_ 100
#define HW_   (H_*W_)
#define ONE_V_ 0.60653065971263342f   // exp(-0.5)
#define TWO_V_ 0.36787944117144233f   // exp(-1.0)
#define TK_P  16                      // partitions per batch in target part

#define FOCAL_ITERS   16
#define FOCAL_BLOCKS  ((B_*C_*HW_) / 4 / 256 / FOCAL_ITERS)   // 1280
#define TK_BLOCKS     (B_*TK_P)                               // 256
#define HEAT_BLOCKS   B_                                      // 16
#define TOTAL_BLOCKS  (FOCAL_BLOCKS + TK_BLOCKS + HEAT_BLOCKS)

// ws float layout (all partials written unconditionally every call):
//   [0,1280)     focal per-block partials
//   [1280,1536)  target offset-sum per-block
//   [1536,1792)  target size-sum per-block
//   [1792,2048)  target count per-block (as float)
//   [2048,2064)  heat correction per-batch
#define WS_TOFF 1280
#define WS_TSIZ 1536
#define WS_TCNT 1792
#define WS_HEAT 2048

__device__ __forceinline__ float block_reduce(float v, float* sbuf) {
    __syncthreads();                       // protect sbuf reuse across calls
    #pragma unroll
    for (int o = 32; o > 0; o >>= 1) v += __shfl_down(v, o, 64);
    int lane = threadIdx.x & 63;
    int wid  = threadIdx.x >> 6;
    if (lane == 0) sbuf[wid] = v;
    __syncthreads();
    float r = 0.0f;
    if (wid == 0) {
        if (lane < 4) r = sbuf[lane];
        #pragma unroll
        for (int o = 2; o > 0; o >>= 1) r += __shfl_down(r, o, 64);
    }
    return r;  // valid on thread 0
}

// One fused kernel: focal blocks + target blocks + heat blocks, all
// independent, all writing private ws slots (no atomics, no init kernel).
// R4: LDS scan loops vectorized to ds_read_b128 + unroll — R3's scalar
// dynamic-trip LDS loops ran at ~120cyc/iter latency (71us critical path).
__global__ __launch_bounds__(256) void main_kernel(
        const float* __restrict__ cls_pred,
        const float* __restrict__ offset_pred,
        const float* __restrict__ size_pred,
        const float* __restrict__ gt_box,
        const int* __restrict__ gt_class,
        float* __restrict__ ws) {
    __shared__ float smem[4096 + 1088];   // target svals | heat arrays | sbuf
    int bid = blockIdx.x;
    int tid = threadIdx.x;

    if (bid < FOCAL_BLOCKS) {
        // ---- focal base: gt==0 term p^2*log(1-p) for every cell ----
        float* sbuf = smem;
        const float4* cp = (const float4*)cls_pred;
        size_t base = (size_t)bid * 256 * FOCAL_ITERS + tid;
        float s = 0.0f;
        #pragma unroll
        for (int it = 0; it < FOCAL_ITERS; it++) {
            float4 v = cp[base + (size_t)it * 256];
            float p;
            p = fminf(fmaxf(v.x, 1e-4f), 0.9999f); s += p*p*__logf(1.0f - p);
            p = fminf(fmaxf(v.y, 1e-4f), 0.9999f); s += p*p*__logf(1.0f - p);
            p = fminf(fmaxf(v.z, 1e-4f), 0.9999f); s += p*p*__logf(1.0f - p);
            p = fminf(fmaxf(v.w, 1e-4f), 0.9999f); s += p*p*__logf(1.0f - p);
        }
        float r = block_reduce(s, sbuf);
        if (tid == 0) ws[bid] = r;

    } else if (bid < FOCAL_BLOCKS + TK_BLOCKS) {
        // ---- target: CAND smallest cls_pred in window -> L1 sums + count ----
        int tb   = bid - FOCAL_BLOCKS;
        int b    = tb / TK_P;
        int part = tb % TK_P;
        float* svals = smem;          // window <= 64x64
        float* sbuf  = smem + 4096;

        int last = -1; bool anyv = false;
        #pragma unroll
        for (int n = 0; n < N_; n++) {
            if (gt_class[b*N_ + n] != -1) { anyv = true; last = n; }
        }
        int lastc = last < 0 ? 0 : last;
        const float* bx = gt_box + ((size_t)b*N_ + lastc)*4;
        float wv = bx[2] - bx[0];
        float hv = bx[3] - bx[1];
        int gc = gt_class[b*N_ + lastc];
        int ch = gc < 0 ? 0 : gc;
        int cx = (int)floorf(floorf(wv*0.5f)*0.25f);
        int cy = (int)floorf(floorf(hv*0.5f)*0.25f);
        int w4 = (int)floorf(wv*0.25f);
        int h4 = (int)floorf(hv*0.25f);
        // Python // is floor division: arithmetic >>1 matches for all signs
        int left   = max((cx - (w4 >> 1)) >> 1, 0);
        int right  = min((cx + (w4 >> 1)) >> 1, H_/2);
        int top    = max((cy - (h4 >> 1)) >> 1, 0);
        int bottom = min((cy + (h4 >> 1)) >> 1, W_/2);
        int Mw = right - left, Mh = bottom - top;
        int M = (anyv && Mw > 0 && Mh > 0) ? Mw * Mh : 0;

        float offsum = 0.0f, sizsum = 0.0f, csum = 0.0f;
        if (M > 0) {
            const float* cp = cls_pred + ((size_t)b*C_ + ch)*HW_;
            for (int t = tid; t < M; t += 256) {
                int i = left + t / Mh;
                int j = top  + t % Mh;
                svals[t] = cp[i*W_ + j];
            }
            // pad to multiple of 4 so the b128 rank loop never reads garbage
            for (int t = M + tid; t < ((M + 3) & ~3); t += 256) svals[t] = __int_as_float(0x7F800000); // +inf
            __syncthreads();
            float cxf = wv * 0.125f, cyf = hv * 0.125f;   // wv/2/4 exact in fp32
            float off0 = cxf - floorf(cxf);
            float off1 = cyf - floorf(cyf);
            const float4* sv4 = (const float4*)svals;
            int M4 = (M + 3) >> 2;
            for (int t = part*256 + tid; t < M; t += TK_P*256) {
                float v = svals[t];
                int rank = 0;
                // vectorized scan: 4 values per ds_read_b128, unrolled for ILP
                #pragma unroll 4
                for (int kb = 0; kb < M4; kb++) {
                    float4 u = sv4[kb];
                    int k = kb << 2;
                    rank += (u.x < v) || (u.x == v && (k+0) < t);
                    rank += (u.y < v) || (u.y == v && (k+1) < t);
                    rank += (u.z < v) || (u.z == v && (k+2) < t);
                    rank += (u.w < v) || (u.w == v && (k+3) < t);
                }
                if (rank < CAND_) {
                    int i = left + t / Mh;
                    int j = top  + t % Mh;
                    const float* op = offset_pred + (size_t)b*2*HW_ + i*W_ + j;
                    const float* sp = size_pred   + (size_t)b*2*HW_ + i*W_ + j;
                    offsum += fabsf(op[0] - off0) + fabsf(op[HW_] - off1);
                    sizsum += fabsf(sp[0] - wv)   + fabsf(sp[HW_] - hv);
                    csum   += 1.0f;
                }
            }
        }
        float ro = block_reduce(offsum, sbuf);
        float rs = block_reduce(sizsum, sbuf);
        float rc = block_reduce(csum,   sbuf);
        if (tid == 0) {
            ws[WS_TOFF + tb] = ro;
            ws[WS_TSIZ + tb] = rs;
            ws[WS_TCNT + tb] = rc;
        }

    } else {
        // ---- heat: sparse correction of focal terms at gt>0 cells ----
        int b = bid - FOCAL_BLOCKS - TK_BLOCKS;
        int*   ekey  = (int*)smem;          // 512 slots (9*N=450 used, padded)
        float* evalv = smem + 512;
        float* sbuf  = smem + 1024;
        for (int e = tid; e < 512; e += 256) { ekey[e] = -1; evalv[e] = 0.0f; }
        __syncthreads();
        if (tid < N_) {
            int n = tid;
            int gc = gt_class[b*N_ + n];
            if (gc != -1) {
                int ch = gc < 0 ? 0 : gc;
                const float* bx = gt_box + ((size_t)b*N_ + n)*4;
                float wv = bx[2] - bx[0];
                float hv = bx[3] - bx[1];
                int cx = (int)floorf(floorf(wv*0.5f)*0.25f);
                int cy = (int)floorf(floorf(hv*0.5f)*0.25f);
                if (cx >= 0 && cx < H_ && cy >= 0 && cy < W_) {
                    ekey[n*9]  = (ch*H_ + cx)*W_ + cy;
                    evalv[n*9] = 1.0f;
                }
                bool interior = (cx >= 1) && (cy >= 1) && (cx + 1 < H_) && (cy + 1 < W_);
                if (interior) {
                    const int   dxs[8] = {-1,-1,-1, 0, 0, 1, 1, 1};
                    const int   dys[8] = {-1, 0, 1,-1, 1,-1, 0, 1};
                    const float vvs[8] = {TWO_V_,ONE_V_,TWO_V_,ONE_V_,ONE_V_,TWO_V_,ONE_V_,TWO_V_};
                    #pragma unroll
                    for (int q = 0; q < 8; q++) {
                        ekey[n*9+1+q]  = (ch*H_ + cx + dxs[q])*W_ + (cy + dys[q]);
                        evalv[n*9+1+q] = vvs[q];
                    }
                }
            }
        }
        __syncthreads();
        const int4*   ek4 = (const int4*)ekey;
        const float4* ev4 = (const float4*)evalv;
        float corr = 0.0f;
        for (int e = tid; e < 9*N_; e += 256) {
            int k = ekey[e];
            if (k < 0) continue;
            // Branch-free vectorized dedup scan: per-key max g, owner = first argmax.
            float g = 0.0f; int first = -1;
            #pragma unroll 4
            for (int qb = 0; qb < 128; qb++) {
                int4   kq = ek4[qb];
                float4 vq = ev4[qb];
                int q = qb << 2;
                bool h0 = (kq.x == k) & (vq.x > g); g = h0 ? vq.x : g; first = h0 ? q+0 : first;
                bool h1 = (kq.y == k) & (vq.y > g); g = h1 ? vq.y : g; first = h1 ? q+1 : first;
                bool h2 = (kq.z == k) & (vq.z > g); g = h2 ? vq.z : g; first = h2 ? q+2 : first;
                bool h3 = (kq.w == k) & (vq.w > g); g = h3 ? vq.w : g; first = h3 ? q+3 : first;
            }
            if (first != e) continue;
            float praw = cls_pred[(size_t)b*C_*HW_ + k];
            float p  = fminf(fmaxf(praw, 1e-4f), 0.9999f);
            float lm = __logf(1.0f - p);
            float base = p*p*lm;
            float actual;
            if (g == 1.0f) {
                float q1 = 1.0f - p; float q2 = q1*q1;
                actual = q2*q2*__logf(p);
            } else {
                float q1 = 1.0f - g; float q2 = q1*q1;
                actual = q2*q2*p*p*lm;
            }
            corr += actual - base;
        }
        float rc = block_reduce(corr, sbuf);
        if (tid == 0) ws[WS_HEAT + b] = rc;
    }
}

__global__ __launch_bounds__(256) void finalize_kernel(
        const float* __restrict__ ws, float* __restrict__ out) {
    __shared__ double dbuf[16];
    int tid = threadIdx.x;
    double cls = 0.0, off = 0.0, siz = 0.0, cnt = 0.0;
    for (int i = tid; i < FOCAL_BLOCKS; i += 256) cls += (double)ws[i];
    if (tid < HEAT_BLOCKS) cls += (double)ws[WS_HEAT + tid];
    off = (double)ws[WS_TOFF + tid];
    siz = (double)ws[WS_TSIZ + tid];
    cnt = (double)ws[WS_TCNT + tid];
    int lane = tid & 63, wid = tid >> 6;
    #pragma unroll
    for (int o = 32; o > 0; o >>= 1) {
        cls += __shfl_down(cls, o, 64);
        off += __shfl_down(off, o, 64);
        siz += __shfl_down(siz, o, 64);
        cnt += __shfl_down(cnt, o, 64);
    }
    if (lane == 0) {
        dbuf[wid*4+0] = cls; dbuf[wid*4+1] = off;
        dbuf[wid*4+2] = siz; dbuf[wid*4+3] = cnt;
    }
    __syncthreads();
    if (tid == 0) {
        cls = dbuf[0] + dbuf[4] + dbuf[8]  + dbuf[12];
        off = dbuf[1] + dbuf[5] + dbuf[9]  + dbuf[13];
        siz = dbuf[2] + dbuf[6] + dbuf[10] + dbuf[14];
        cnt = dbuf[3] + dbuf[7] + dbuf[11] + dbuf[15];
        int c = (int)(cnt + 0.5);
        double np_ = (double)(c < 1 ? 1 : c);
        out[0] = (float)(-cls / (double)(B_*H_*W_) + off/np_ + 0.1*siz/np_);
    }
}

extern "C" void kernel_launch(void* const* d_in, const int* in_sizes, int n_in,
                              void* d_out, int out_size, void* d_ws, size_t ws_size,
                              hipStream_t stream) {
    const float* cls_pred    = (const float*)d_in[0];
    const float* offset_pred = (const float*)d_in[1];
    const float* size_pred   = (const float*)d_in[2];
    const float* gt_box      = (const float*)d_in[3];
    const int*   gt_class    = (const int*)d_in[4];
    float* out = (float*)d_out;
    float* ws  = (float*)d_ws;

    main_kernel<<<dim3(TOTAL_BLOCKS), dim3(256), 0, stream>>>(
        cls_pred, offset_pred, size_pred, gt_box, gt_class, ws);
    finalize_kernel<<<dim3(1), dim3(256), 0, stream>>>(ws, out);
}